// Round 6
// baseline (308.721 us; speedup 1.0000x reference)
//
#include <hip/hip_runtime.h>
#include <hip/hip_bf16.h>

// B=2, C=512, H=W=64 -> N=4096, 32 groups of 16 channels
#define BATCH 2
#define CDIM 512
#define NDIM 4096
#define NGROUPS 32
#define CHPG 16
#define GN_EPS 1e-6f

typedef __attribute__((ext_vector_type(8))) short bf16x8;   // 8 bf16 = 4 VGPRs
typedef __attribute__((ext_vector_type(4))) float f32x4;
typedef unsigned char uchar;

__device__ __forceinline__ void gl_lds16(const void* g, void* lds) {
  __builtin_amdgcn_global_load_lds((__attribute__((address_space(1))) void*)(g),
                                   (__attribute__((address_space(3))) void*)(lds), 16, 0, 0);
}

__device__ __forceinline__ uchar fp8_of(float v) {
  // OCP e4m3 on gfx950 HW converter
  return (uchar)(__builtin_amdgcn_cvt_pk_fp8_f32(v, 0.f, 0, false) & 0xff);
}

// ---------------- GroupNorm stats, two-stage ----------------
__global__ __launch_bounds__(256) void gn_stats_p1(const float* __restrict__ x,
                                                   float2* __restrict__ part) {
  int blk = blockIdx.x;
  int chunk = blk & 15, bg = blk >> 4;
  const float4* p = (const float4*)(x + (size_t)bg * (CHPG * NDIM) + chunk * 4096);
  float s = 0.f, ss = 0.f;
#pragma unroll
  for (int t = 0; t < 4; t++) {
    float4 v = p[threadIdx.x + t * 256];
    s += v.x + v.y + v.z + v.w;
    ss += v.x * v.x + v.y * v.y + v.z * v.z + v.w * v.w;
  }
  int w = threadIdx.x >> 6, l = threadIdx.x & 63;
#pragma unroll
  for (int off = 32; off > 0; off >>= 1) {
    s += __shfl_down(s, off);
    ss += __shfl_down(ss, off);
  }
  __shared__ float r1[4], r2[4];
  if (l == 0) { r1[w] = s; r2[w] = ss; }
  __syncthreads();
  if (threadIdx.x == 0)
    part[blk] = make_float2(r1[0] + r1[1] + r1[2] + r1[3], r2[0] + r2[1] + r2[2] + r2[3]);
}

__global__ __launch_bounds__(64) void gn_stats_p2(const float2* __restrict__ part,
                                                  float2* __restrict__ stats) {
  int bg = threadIdx.x;  // 64
  float s = 0.f, ss = 0.f;
#pragma unroll
  for (int c = 0; c < 16; c++) {
    float2 v = part[bg * 16 + c];
    s += v.x; ss += v.y;
  }
  const float inv = 1.0f / (CHPG * NDIM);
  float mean = s * inv;
  float var = ss * inv - mean * mean;
  stats[bg] = make_float2(mean, rsqrtf(var + GN_EPS));
}

// ------ GroupNorm apply + transpose to channel-last bf16: h_t[b][n][c] ------
__global__ __launch_bounds__(256) void gn_apply_t(const float* __restrict__ x,
                                                  const float2* __restrict__ stats,
                                                  const float* __restrict__ w,
                                                  const float* __restrict__ bias,
                                                  __hip_bfloat16* __restrict__ ht) {
  __shared__ __hip_bfloat16 tile[64][66];
  int b = blockIdx.z, c0 = blockIdx.y * 64, n0 = blockIdx.x * 64;
  int tq = threadIdx.x >> 6;
  int tl = threadIdx.x & 63;
#pragma unroll
  for (int i = 0; i < 16; i++) {
    int cl = tq * 16 + i;
    int c = c0 + cl;
    float2 st = stats[b * NGROUPS + (c >> 4)];
    float v = x[((size_t)b * CDIM + c) * NDIM + n0 + tl];
    v = (v - st.x) * st.y * w[c] + bias[c];
    tile[tl][cl] = __float2bfloat16(v);
  }
  __syncthreads();
#pragma unroll
  for (int i = 0; i < 16; i++) {
    int nl = tq * 16 + i;
    ht[((size_t)b * NDIM + n0 + nl) * CDIM + c0 + tl] = tile[nl][tl];
  }
}

// ------------- fp32 -> bf16 for the four 512x512 weights -------------
__global__ __launch_bounds__(256) void cvt_w(const float* __restrict__ a, const float* __restrict__ b,
                                             const float* __restrict__ c, const float* __restrict__ d,
                                             __hip_bfloat16* __restrict__ o) {
  int i = blockIdx.x * 256 + threadIdx.x;
  o[i]          = __float2bfloat16(a[i]);
  o[i + 262144] = __float2bfloat16(b[i]);
  o[i + 524288] = __float2bfloat16(c[i]);
  o[i + 786432] = __float2bfloat16(d[i]);
}

// ---------------- MFMA NT GEMM (bf16), MT x NT tile ----------------
// C[m][n] = scale * sum_k A[m][k]*B[n][k]  (+bias) (+res)
// OUT_MODE: 0 = f32, 1 = bf16, 2 = fp8 e4m3.
// BIAS_MODE: 0 none, 1 bias[m], 2 bias[n]. STATS (needs 128x128): per-block
// column max & sum-of-exp to pmax/psum. SWIZ (needs grid (8,32,z)): co-locate
// the 8 blocks sharing an A row-tile on one XCD.
template <int MT, int NT, int BIAS_MODE, bool HAS_RES, int OUT_MODE, bool STATS, bool SWIZ, int MINB>
__global__ __launch_bounds__(256, MINB) void mfma_gemm_nt(
    const __hip_bfloat16* __restrict__ A, const __hip_bfloat16* __restrict__ B,
    const float* __restrict__ bias, const float* __restrict__ res,
    void* __restrict__ Cout, float* __restrict__ pmax_g, float* __restrict__ psum_g,
    int M, int N, int K, long sA, long sB, long sC, float scale) {
  constexpr int MTI = MT / 32, NTI = NT / 32;   // 16x16 acc tiles per wave
  __shared__ __hip_bfloat16 As[MT * 32];
  __shared__ __hip_bfloat16 Bs[NT * 32];
  const int tid = threadIdx.x;
  const int w = tid >> 6, l = tid & 63;
  const int wy = w >> 1, wx = w & 1;
  const int bz = blockIdx.z;
  int bx = blockIdx.x, by = blockIdx.y;
  if constexpr (SWIZ) {
    int l2 = by * 8 + bx;
    int xcd = l2 & 7, s = l2 >> 3;
    by = xcd + (s & 3) * 8;
    bx = s >> 2;
  }
  const int m0 = by * MT, n0 = bx * NT;
  f32x4 acc[MTI][NTI] = {};
  const int arow = w * (MT / 4) + (l >> 2);
  const int brow = w * (NT / 4) + (l >> 2);
  const char* Ag = (const char*)(A + (size_t)bz * sA + (size_t)(m0 + arow) * K) + (l & 3) * 16;
  const char* Bg = (const char*)(B + (size_t)bz * sB + (size_t)(n0 + brow) * K) + (l & 3) * 16;
  char* Al = (char*)As + w * (MT * 16);
  char* Bl = (char*)Bs + w * (NT * 16);
  const size_t radv = (size_t)K * 32;  // +16 rows (bf16)
  for (int k0 = 0; k0 < K; k0 += 32) {
    gl_lds16(Ag, Al);
    if (MT == 128) gl_lds16(Ag + radv, Al + 1024);
    gl_lds16(Bg, Bl);
    if (NT == 128) gl_lds16(Bg + radv, Bl + 1024);
    Ag += 64; Bg += 64;
    __syncthreads();
    bf16x8 af[MTI], bfr[NTI];
#pragma unroll
    for (int mt = 0; mt < MTI; mt++)
      af[mt] = *(const bf16x8*)(As + (wy * (MT / 2) + mt * 16 + (l & 15)) * 32 + (l >> 4) * 8);
#pragma unroll
    for (int nt = 0; nt < NTI; nt++)
      bfr[nt] = *(const bf16x8*)(Bs + (wx * (NT / 2) + nt * 16 + (l & 15)) * 32 + (l >> 4) * 8);
#pragma unroll
    for (int mt = 0; mt < MTI; mt++)
#pragma unroll
      for (int nt = 0; nt < NTI; nt++)
        acc[mt][nt] = __builtin_amdgcn_mfma_f32_16x16x32_bf16(af[mt], bfr[nt], acc[mt][nt], 0, 0, 0);
    __syncthreads();
  }
  // epilogue: D row = (l>>4)*4 + r, col = l&15
  const size_t cbase = (size_t)bz * sC;
#pragma unroll
  for (int mt = 0; mt < MTI; mt++) {
#pragma unroll
    for (int r = 0; r < 4; r++) {
      const int m = m0 + wy * (MT / 2) + mt * 16 + (l >> 4) * 4 + r;
      float bv = (BIAS_MODE == 1) ? bias[m] : 0.f;
#pragma unroll
      for (int nt = 0; nt < NTI; nt++) {
        const int n = n0 + wx * (NT / 2) + nt * 16 + (l & 15);
        float v = acc[mt][nt][r] * scale + bv;
        if (BIAS_MODE == 2) v += bias[n];
        if (HAS_RES) v += res[cbase + (size_t)m * N + n];
        if (OUT_MODE == 0) ((float*)Cout)[cbase + (size_t)m * N + n] = v;
        else if (OUT_MODE == 1) ((__hip_bfloat16*)Cout)[cbase + (size_t)m * N + n] = __float2bfloat16(v);
        else ((uchar*)Cout)[cbase + (size_t)m * N + n] = fp8_of(v);
      }
    }
  }
  if constexpr (STATS) {
    float* sred1 = (float*)As;          // [w][nt][16]
    float* sred2 = (float*)As + 512;
    float cm[NTI];
#pragma unroll
    for (int nt = 0; nt < NTI; nt++) {
      float m = -1e30f;
#pragma unroll
      for (int mt = 0; mt < MTI; mt++)
#pragma unroll
        for (int r = 0; r < 4; r++) m = fmaxf(m, acc[mt][nt][r] * scale);
      m = fmaxf(m, __shfl_xor(m, 16));
      m = fmaxf(m, __shfl_xor(m, 32));
      if (l < 16) sred1[(w * NTI + nt) * 16 + l] = m;
    }
    __syncthreads();
#pragma unroll
    for (int nt = 0; nt < NTI; nt++) {
      float bm = fmaxf(sred1[(wx * NTI + nt) * 16 + (l & 15)],
                       sred1[((2 + wx) * NTI + nt) * 16 + (l & 15)]);
      cm[nt] = bm;
      float s = 0.f;
#pragma unroll
      for (int mt = 0; mt < MTI; mt++)
#pragma unroll
        for (int r = 0; r < 4; r++) s += __expf(acc[mt][nt][r] * scale - bm);
      s += __shfl_xor(s, 16);
      s += __shfl_xor(s, 32);
      if (l < 16) sred2[(w * NTI + nt) * 16 + l] = s;
    }
    __syncthreads();
    if (wy == 0 && l < 16) {
#pragma unroll
      for (int nt = 0; nt < NTI; nt++) {
        float stot = sred2[(wx * NTI + nt) * 16 + l] + sred2[((2 + wx) * NTI + nt) * 16 + l];
        int i = n0 + wx * 64 + nt * 16 + l;
        size_t idx = ((size_t)bz * gridDim.y + blockIdx.y) * N + i;
        pmax_g[idx] = cm[nt];
        psum_g[idx] = stot;
      }
    }
  }
}

// ---------------- PV GEMM, fp8 x fp8 (e4m3), 128x64 tile, BK=64 ----------------
// ht2[m=j][n=c] = (1/256) * sum_k Pq[j][k] * vq[c][k]; out bf16 [4096, 512]
__global__ __launch_bounds__(256, 2) void mfma_pv_fp8(
    const uchar* __restrict__ A,   // Pq [B][4096][4096]
    const uchar* __restrict__ Bv,  // vq [B][512][4096]
    __hip_bfloat16* __restrict__ Cout) {  // [B][4096][512]
  __shared__ uchar As[128 * 64];  // 8 KB
  __shared__ uchar Bs[64 * 64];   // 4 KB
  const int tid = threadIdx.x;
  const int w = tid >> 6, l = tid & 63;
  const int wy = w >> 1, wx = w & 1;
  const int bz = blockIdx.z;
  int bx = blockIdx.x, by = blockIdx.y;  // grid (8, 32, B)
  {  // XCD swizzle: 8 A-sharing partners on one XCD
    int l2 = by * 8 + bx;
    int xcd = l2 & 7, s = l2 >> 3;
    by = xcd + (s & 3) * 8;
    bx = s >> 2;
  }
  const int m0 = by * 128, n0 = bx * 64;
  const size_t K = 4096;
  f32x4 acc[4][2] = {};
  // staging: one issue = 64 lanes x 16B = 16 rows x 64B (fp8)
  const int arow = w * 32 + (l >> 2);   // 2 issues per wave for 128 rows
  const int brow = w * 16 + (l >> 2);   // 1 issue per wave for 64 rows
  const uchar* Ag = A + (size_t)bz * (4096 * 4096) + (size_t)(m0 + arow) * K + (l & 3) * 16;
  const uchar* Bg = Bv + (size_t)bz * (512 * 4096) + (size_t)(n0 + brow) * K + (l & 3) * 16;
  uchar* Al = As + w * 2048;   // + l*16 implied by gl_lds16 lane mapping
  uchar* Bl = Bs + w * 1024;
  const size_t radv = K * 16;  // +16 rows
  for (int k0 = 0; k0 < 4096; k0 += 64) {
    gl_lds16(Ag, Al);
    gl_lds16(Ag + radv, Al + 1024);
    gl_lds16(Bg, Bl);
    Ag += 64; Bg += 64;
    __syncthreads();
#pragma unroll
    for (int ks = 0; ks < 2; ks++) {
      long af[4], bfr[2];
#pragma unroll
      for (int mt = 0; mt < 4; mt++)
        af[mt] = *(const long*)(As + (wy * 64 + mt * 16 + (l & 15)) * 64 + (l >> 4) * 8 + ks * 32);
#pragma unroll
      for (int nt = 0; nt < 2; nt++)
        bfr[nt] = *(const long*)(Bs + (wx * 32 + nt * 16 + (l & 15)) * 64 + (l >> 4) * 8 + ks * 32);
#pragma unroll
      for (int mt = 0; mt < 4; mt++)
#pragma unroll
        for (int nt = 0; nt < 2; nt++)
          acc[mt][nt] = __builtin_amdgcn_mfma_f32_16x16x32_fp8_fp8(af[mt], bfr[nt], acc[mt][nt], 0, 0, 0);
    }
    __syncthreads();
  }
  const size_t cbase = (size_t)bz * (4096 * 512);
  const float inv256 = 1.0f / 256.0f;
#pragma unroll
  for (int mt = 0; mt < 4; mt++)
#pragma unroll
    for (int r = 0; r < 4; r++) {
      const int m = m0 + wy * 64 + mt * 16 + (l >> 4) * 4 + r;
#pragma unroll
      for (int nt = 0; nt < 2; nt++) {
        const int n = n0 + wx * 32 + nt * 16 + (l & 15);
        Cout[cbase + (size_t)m * 512 + n] = __float2bfloat16(acc[mt][nt][r] * inv256);
      }
    }
}

// ---------------- softmax combine + apply ----------------
__global__ __launch_bounds__(256) void softmax_comb(const float* __restrict__ pmax,
                                                    const float* __restrict__ psum,
                                                    float* __restrict__ cmax, float* __restrict__ cinv) {
  int idx = blockIdx.x * 256 + threadIdx.x;  // b*NDIM + i
  int b = idx >> 12, i = idx & (NDIM - 1);
  float M = -1e30f;
  for (int bc = 0; bc < 32; bc++) M = fmaxf(M, pmax[((size_t)b * 32 + bc) * NDIM + i]);
  float s = 0.f;
  for (int bc = 0; bc < 32; bc++) {
    size_t o = ((size_t)b * 32 + bc) * NDIM + i;
    s += psum[o] * __expf(pmax[o] - M);
  }
  cmax[idx] = M;
  cinv[idx] = 1.0f / s;
}

// read St (bf16), write Pq = fp8(256 * exp(s - M) * inv); one j-row per block
__global__ __launch_bounds__(256) void softmax_apply(const __hip_bfloat16* __restrict__ St,
                                                     uchar* __restrict__ Pq,
                                                     const float* __restrict__ cmax,
                                                     const float* __restrict__ cinv) {
  int b = blockIdx.y;
  size_t row = blockIdx.x;
  int i0 = threadIdx.x * 16;
  const __hip_bfloat16* p = St + ((size_t)b * NDIM + row) * NDIM + i0;
  uchar* q = Pq + ((size_t)b * NDIM + row) * NDIM + i0;
  const float4* pm = (const float4*)(cmax + (size_t)b * NDIM + i0);
  const float4* pz = (const float4*)(cinv + (size_t)b * NDIM + i0);
  bf16x8 d0 = *(const bf16x8*)p;
  bf16x8 d1 = *(const bf16x8*)(p + 8);
  float4 M4[4], Z4[4];
#pragma unroll
  for (int t = 0; t < 4; t++) { M4[t] = pm[t]; Z4[t] = pz[t]; }
  const float* Mf = (const float*)M4;
  const float* Zf = (const float*)Z4;
  float f[16];
#pragma unroll
  for (int e = 0; e < 8; e++) {
    union { short s; __hip_bfloat16 h; } u; u.s = d0[e];
    f[e] = __expf(__bfloat162float(u.h) - Mf[e]) * Zf[e] * 256.0f;
  }
#pragma unroll
  for (int e = 0; e < 8; e++) {
    union { short s; __hip_bfloat16 h; } u; u.s = d1[e];
    f[8 + e] = __expf(__bfloat162float(u.h) - Mf[8 + e]) * Zf[8 + e] * 256.0f;
  }
  int out[4];
#pragma unroll
  for (int t = 0; t < 4; t++) {
    int v = __builtin_amdgcn_cvt_pk_fp8_f32(f[t * 4 + 0], f[t * 4 + 1], 0, false);
    v = __builtin_amdgcn_cvt_pk_fp8_f32(f[t * 4 + 2], f[t * 4 + 3], v, true);
    out[t] = v;
  }
  *(int4*)q = make_int4(out[0], out[1], out[2], out[3]);
}

extern "C" void kernel_launch(void* const* d_in, const int* in_sizes, int n_in,
                              void* d_out, int out_size, void* d_ws, size_t ws_size,
                              hipStream_t stream) {
  const float* x      = (const float*)d_in[0];
  const float* norm_w = (const float*)d_in[1];
  const float* norm_b = (const float*)d_in[2];
  const float* wq = (const float*)d_in[3];
  const float* bq = (const float*)d_in[4];
  const float* wk = (const float*)d_in[5];
  const float* bk = (const float*)d_in[6];
  const float* wv = (const float*)d_in[7];
  const float* bv = (const float*)d_in[8];
  const float* wp = (const float*)d_in[9];
  const float* bp = (const float*)d_in[10];
  float* out = (float*)d_out;

  const long CN = (long)CDIM * NDIM;
  const long NN = (long)NDIM * NDIM;
  char* p = (char*)d_ws;
  auto carve = [&](size_t bytes) { char* r = p; p += (bytes + 255) & ~(size_t)255; return r; };
  __hip_bfloat16* h_t  = (__hip_bfloat16*)carve(BATCH * CN * 2);  // [B,N,C]
  __hip_bfloat16* wb   = (__hip_bfloat16*)carve(4 * 512 * 512 * 2);
  __hip_bfloat16* q_t  = (__hip_bfloat16*)carve(BATCH * CN * 2);  // [B,N,C]
  __hip_bfloat16* k_t  = (__hip_bfloat16*)carve(BATCH * CN * 2);  // [B,N,C]
  uchar*          vq   = (uchar*)carve(BATCH * CN);               // [B,C,N] fp8
  __hip_bfloat16* ht2  = (__hip_bfloat16*)carve(BATCH * CN * 2);  // [B,N,C]
  __hip_bfloat16* St   = (__hip_bfloat16*)carve(BATCH * NN * 2);  // [B,N,N] S^T (scores)
  uchar*          Pq   = (uchar*)carve(BATCH * NN);               // [B,N,N] P^T fp8 (x256)
  float2* stats = (float2*)carve(BATCH * NGROUPS * sizeof(float2));
  float2* gnpart = (float2*)carve(1024 * sizeof(float2));
  float* pmax = (float*)carve((size_t)BATCH * 32 * NDIM * 4);
  float* psum = (float*)carve((size_t)BATCH * 32 * NDIM * 4);
  float* cmax = (float*)carve(BATCH * NDIM * 4);
  float* cinv = (float*)carve(BATCH * NDIM * 4);
  __hip_bfloat16* wbq = wb;
  __hip_bfloat16* wbk = wb + 262144;
  __hip_bfloat16* wbv = wb + 524288;
  __hip_bfloat16* wbp = wb + 786432;

  const float scale = 0.044194173824159216f;  // 512^-0.5

  gn_stats_p1<<<dim3(1024), 256, 0, stream>>>(x, gnpart);
  gn_stats_p2<<<dim3(1), 64, 0, stream>>>(gnpart, stats);
  gn_apply_t<<<dim3(NDIM / 64, CDIM / 64, BATCH), 256, 0, stream>>>(x, stats, norm_w, norm_b, h_t);
  cvt_w<<<dim3(1024), 256, 0, stream>>>(wq, wk, wv, wp, wb);

  // q_t = h_t @ wq^T + bq -> [N, C] bf16   (SWIZ: A=h_t shared by 8 x-partners)
  mfma_gemm_nt<128, 64, 2, false, 1, false, true, 2><<<dim3(8, 32, BATCH), 256, 0, stream>>>(
      h_t, wbq, bq, nullptr, q_t, nullptr, nullptr, NDIM, CDIM, CDIM, CN, 0, CN, 1.0f);
  // k_t = h_t @ wk^T + bk -> [N, C] bf16
  mfma_gemm_nt<128, 64, 2, false, 1, false, true, 2><<<dim3(8, 32, BATCH), 256, 0, stream>>>(
      h_t, wbk, bk, nullptr, k_t, nullptr, nullptr, NDIM, CDIM, CDIM, CN, 0, CN, 1.0f);
  // vq = fp8(wv @ h_t^T + bv) -> [C, N]
  mfma_gemm_nt<64, 128, 1, false, 2, false, false, 2><<<dim3(32, 8, BATCH), 256, 0, stream>>>(
      wbv, h_t, bv, nullptr, vq, nullptr, nullptr, CDIM, NDIM, CDIM, 0, CN, CN, 1.0f);
  // St = k_t @ q_t^T * scale -> [N, N] bf16, fused column stats; 3 blocks/CU
  mfma_gemm_nt<128, 128, 0, false, 1, true, false, 3><<<dim3(32, 32, BATCH), 256, 0, stream>>>(
      k_t, q_t, nullptr, nullptr, St, pmax, psum, NDIM, NDIM, CDIM, CN, CN, NN, scale);
  softmax_comb<<<dim3(32), 256, 0, stream>>>(pmax, psum, cmax, cinv);
  softmax_apply<<<dim3(NDIM, BATCH), 256, 0, stream>>>(St, Pq, cmax, cinv);
  // ht2 = (Pq @ vq^T)/256 -> [N, C] bf16   (fp8 MFMA, XCD swizzle)
  mfma_pv_fp8<<<dim3(8, 32, BATCH), 256, 0, stream>>>(Pq, vq, ht2);
  // out = wp @ ht2^T + bp + x -> [C, N] fp32
  mfma_gemm_nt<64, 128, 1, true, 0, false, false, 2><<<dim3(32, 8, BATCH), 256, 0, stream>>>(
      wbp, ht2, bp, x, out, nullptr, nullptr, CDIM, NDIM, CDIM, 0, CN, CN, 1.0f);
}

// Round 8
// 271.365 us; speedup vs baseline: 1.1377x; 1.1377x over previous
//
#include <hip/hip_runtime.h>
#include <hip/hip_bf16.h>

// B=2, C=512, H=W=64 -> N=4096, 32 groups of 16 channels
#define BATCH 2
#define CDIM 512
#define NDIM 4096
#define NGROUPS 32
#define CHPG 16
#define GN_EPS 1e-6f

typedef __attribute__((ext_vector_type(8))) short bf16x8;   // 8 bf16 = 4 VGPRs
typedef __attribute__((ext_vector_type(4))) float f32x4;

__device__ __forceinline__ void gl_lds16(const void* g, void* lds) {
  __builtin_amdgcn_global_load_lds((__attribute__((address_space(1))) void*)(g),
                                   (__attribute__((address_space(3))) void*)(lds), 16, 0, 0);
}

template <int N>
__device__ __forceinline__ void wait_vmcnt() {
  if constexpr (N == 2) asm volatile("s_waitcnt vmcnt(2)" ::: "memory");
  else if constexpr (N == 3) asm volatile("s_waitcnt vmcnt(3)" ::: "memory");
  else asm volatile("s_waitcnt vmcnt(4)" ::: "memory");
}

__device__ __forceinline__ void raw_barrier() {
  asm volatile("s_barrier" ::: "memory");
}

// ---------------- GroupNorm stats, two-stage ----------------
__global__ __launch_bounds__(256) void gn_stats_p1(const float* __restrict__ x,
                                                   float2* __restrict__ part) {
  int blk = blockIdx.x;
  int chunk = blk & 15, bg = blk >> 4;
  const float4* p = (const float4*)(x + (size_t)bg * (CHPG * NDIM) + chunk * 4096);
  float s = 0.f, ss = 0.f;
#pragma unroll
  for (int t = 0; t < 4; t++) {
    float4 v = p[threadIdx.x + t * 256];
    s += v.x + v.y + v.z + v.w;
    ss += v.x * v.x + v.y * v.y + v.z * v.z + v.w * v.w;
  }
  int w = threadIdx.x >> 6, l = threadIdx.x & 63;
#pragma unroll
  for (int off = 32; off > 0; off >>= 1) {
    s += __shfl_down(s, off);
    ss += __shfl_down(ss, off);
  }
  __shared__ float r1[4], r2[4];
  if (l == 0) { r1[w] = s; r2[w] = ss; }
  __syncthreads();
  if (threadIdx.x == 0)
    part[blk] = make_float2(r1[0] + r1[1] + r1[2] + r1[3], r2[0] + r2[1] + r2[2] + r2[3]);
}

__global__ __launch_bounds__(64) void gn_stats_p2(const float2* __restrict__ part,
                                                  float2* __restrict__ stats) {
  int bg = threadIdx.x;  // 64
  float s = 0.f, ss = 0.f;
#pragma unroll
  for (int c = 0; c < 16; c++) {
    float2 v = part[bg * 16 + c];
    s += v.x; ss += v.y;
  }
  const float inv = 1.0f / (CHPG * NDIM);
  float mean = s * inv;
  float var = ss * inv - mean * mean;
  stats[bg] = make_float2(mean, rsqrtf(var + GN_EPS));
}

// ------ GroupNorm apply + transpose to channel-last bf16: h_t[b][n][c] ------
__global__ __launch_bounds__(256) void gn_apply_t(const float* __restrict__ x,
                                                  const float2* __restrict__ stats,
                                                  const float* __restrict__ w,
                                                  const float* __restrict__ bias,
                                                  __hip_bfloat16* __restrict__ ht) {
  __shared__ __hip_bfloat16 tile[64][66];
  int b = blockIdx.z, c0 = blockIdx.y * 64, n0 = blockIdx.x * 64;
  int tq = threadIdx.x >> 6;
  int tl = threadIdx.x & 63;
#pragma unroll
  for (int i = 0; i < 16; i++) {
    int cl = tq * 16 + i;
    int c = c0 + cl;
    float2 st = stats[b * NGROUPS + (c >> 4)];
    float v = x[((size_t)b * CDIM + c) * NDIM + n0 + tl];
    v = (v - st.x) * st.y * w[c] + bias[c];
    tile[tl][cl] = __float2bfloat16(v);
  }
  __syncthreads();
#pragma unroll
  for (int i = 0; i < 16; i++) {
    int nl = tq * 16 + i;
    ht[((size_t)b * NDIM + n0 + nl) * CDIM + c0 + tl] = tile[nl][tl];
  }
}

// ------------- fp32 -> bf16 for the four 512x512 weights -------------
__global__ __launch_bounds__(256) void cvt_w(const float* __restrict__ a, const float* __restrict__ b,
                                             const float* __restrict__ c, const float* __restrict__ d,
                                             __hip_bfloat16* __restrict__ o) {
  int i = blockIdx.x * 256 + threadIdx.x;
  o[i]          = __float2bfloat16(a[i]);
  o[i + 262144] = __float2bfloat16(b[i]);
  o[i + 524288] = __float2bfloat16(c[i]);
  o[i + 786432] = __float2bfloat16(d[i]);
}

// ---------------- MFMA NT GEMM, software-pipelined (dbuf + vmcnt(N)) --------
// C[m][n] = scale * sum_k A[m][k]*B[n][k]  (+bias) (+res)
// A: [M,K] bf16, B: [N,K] bf16, row-major. BK=32, 4 waves (2x2).
// OUT_MODE: 0 f32, 1 bf16. BIAS_MODE: 0 none, 1 bias[m], 2 bias[n].
// STATS (128x128 only): per-block column max/sum-of-exp. SWIZ (grid (8,32,z)):
// co-locate the 8 blocks sharing an A row-tile on one XCD.
// K-loop: double-buffered LDS; prefetch tile t+1, s_waitcnt vmcnt(NL) waits
// only tile t's loads; raw s_barrier (no vmcnt(0) drain).
template <int MT, int NT, int BIAS_MODE, bool HAS_RES, int OUT_MODE, bool STATS, bool SWIZ, int MINB>
__global__ __launch_bounds__(256, MINB) void mfma_gemm_nt(
    const __hip_bfloat16* __restrict__ A, const __hip_bfloat16* __restrict__ B,
    const float* __restrict__ bias, const float* __restrict__ res,
    void* __restrict__ Cout, float* __restrict__ pmax_g, float* __restrict__ psum_g,
    int M, int N, int K, long sA, long sB, long sC, float scale) {
  constexpr int MTI = MT / 32, NTI = NT / 32;     // 16x16 acc tiles per wave
  constexpr int ABYT = MT * 64;                    // bytes per A tile (MT x 32 bf16)
  constexpr int BBYT = NT * 64;
  constexpr int BUFB = ABYT + BBYT;                // one double-buffer slot
  constexpr int NL = (MT == 128 ? 2 : 1) + (NT == 128 ? 2 : 1);
  __shared__ char smem[2 * BUFB];
  const int tid = threadIdx.x;
  const int w = tid >> 6, l = tid & 63;
  const int wy = w >> 1, wx = w & 1;
  const int bz = blockIdx.z;
  int bx = blockIdx.x, by = blockIdx.y;
  if constexpr (SWIZ) {
    int l2 = by * 8 + bx;
    int xcd = l2 & 7, s = l2 >> 3;
    by = xcd + (s & 3) * 8;
    bx = s >> 2;
  }
  const int m0 = by * MT, n0 = bx * NT;
  f32x4 acc[MTI][NTI] = {};
  // staging: one gl_lds16 issue = 64 lanes x 16B = 16 rows x 64B
  const int arow = w * (MT / 4) + (l >> 2);
  const int brow = w * (NT / 4) + (l >> 2);
  const char* Ag = (const char*)(A + (size_t)bz * sA + (size_t)(m0 + arow) * K) + (l & 3) * 16;
  const char* Bg = (const char*)(B + (size_t)bz * sB + (size_t)(n0 + brow) * K) + (l & 3) * 16;
  const size_t radv = (size_t)K * 32;  // +16 rows in bytes (bf16)
  const int woffA = w * (MT * 16);     // per-wave chunk within a buffer
  const int woffB = ABYT + w * (NT * 16);

  auto issue = [&](int buf) {
    char* base = smem + buf * BUFB;
    gl_lds16(Ag, base + woffA);
    if (MT == 128) gl_lds16(Ag + radv, base + woffA + 1024);
    gl_lds16(Bg, base + woffB);
    if (NT == 128) gl_lds16(Bg + radv, base + woffB + 1024);
    Ag += 64; Bg += 64;
  };

  issue(0);  // prologue: tile 0 -> buf 0
  const int T = K / 32;
  for (int t = 0; t < T; t++) {
    issue((t + 1) & 1);       // prefetch tile t+1 (last iter reads 64B past tile row end — within allocation)
    wait_vmcnt<NL>();         // tile t's loads done; t+1's stay in flight
    raw_barrier();
    const __hip_bfloat16* As = (const __hip_bfloat16*)(smem + (t & 1) * BUFB);
    const __hip_bfloat16* Bs = (const __hip_bfloat16*)(smem + (t & 1) * BUFB + ABYT);
    bf16x8 af[MTI], bfr[NTI];
#pragma unroll
    for (int mt = 0; mt < MTI; mt++)
      af[mt] = *(const bf16x8*)(As + (wy * (MT / 2) + mt * 16 + (l & 15)) * 32 + (l >> 4) * 8);
#pragma unroll
    for (int nt = 0; nt < NTI; nt++)
      bfr[nt] = *(const bf16x8*)(Bs + (wx * (NT / 2) + nt * 16 + (l & 15)) * 32 + (l >> 4) * 8);
#pragma unroll
    for (int mt = 0; mt < MTI; mt++)
#pragma unroll
      for (int nt = 0; nt < NTI; nt++)
        acc[mt][nt] = __builtin_amdgcn_mfma_f32_16x16x32_bf16(af[mt], bfr[nt], acc[mt][nt], 0, 0, 0);
    raw_barrier();            // all waves done reading buf[t&1] before tile t+2 overwrites it
  }
  // epilogue: D row = (l>>4)*4 + r, col = l&15
  const size_t cbase = (size_t)bz * sC;
#pragma unroll
  for (int mt = 0; mt < MTI; mt++) {
#pragma unroll
    for (int r = 0; r < 4; r++) {
      const int m = m0 + wy * (MT / 2) + mt * 16 + (l >> 4) * 4 + r;
      float bv = (BIAS_MODE == 1) ? bias[m] : 0.f;
#pragma unroll
      for (int nt = 0; nt < NTI; nt++) {
        const int n = n0 + wx * (NT / 2) + nt * 16 + (l & 15);
        float v = acc[mt][nt][r] * scale + bv;
        if (BIAS_MODE == 2) v += bias[n];
        if (HAS_RES) v += res[cbase + (size_t)m * N + n];
        if (OUT_MODE == 0) ((float*)Cout)[cbase + (size_t)m * N + n] = v;
        else ((__hip_bfloat16*)Cout)[cbase + (size_t)m * N + n] = __float2bfloat16(v);
      }
    }
  }
  if constexpr (STATS) {
    float* sred1 = (float*)smem;          // [w][nt][16]
    float* sred2 = (float*)smem + 512;
    float cm[NTI];
    __syncthreads();  // ensure K-loop LDS reads done before reuse
#pragma unroll
    for (int nt = 0; nt < NTI; nt++) {
      float m = -1e30f;
#pragma unroll
      for (int mt = 0; mt < MTI; mt++)
#pragma unroll
        for (int r = 0; r < 4; r++) m = fmaxf(m, acc[mt][nt][r] * scale);
      m = fmaxf(m, __shfl_xor(m, 16));
      m = fmaxf(m, __shfl_xor(m, 32));
      if (l < 16) sred1[(w * NTI + nt) * 16 + l] = m;
    }
    __syncthreads();
#pragma unroll
    for (int nt = 0; nt < NTI; nt++) {
      float bm = fmaxf(sred1[(wx * NTI + nt) * 16 + (l & 15)],
                       sred1[((2 + wx) * NTI + nt) * 16 + (l & 15)]);
      cm[nt] = bm;
      float s = 0.f;
#pragma unroll
      for (int mt = 0; mt < MTI; mt++)
#pragma unroll
        for (int r = 0; r < 4; r++) s += __expf(acc[mt][nt][r] * scale - bm);
      s += __shfl_xor(s, 16);
      s += __shfl_xor(s, 32);
      if (l < 16) sred2[(w * NTI + nt) * 16 + l] = s;
    }
    __syncthreads();
    if (wy == 0 && l < 16) {
#pragma unroll
      for (int nt = 0; nt < NTI; nt++) {
        float stot = sred2[(wx * NTI + nt) * 16 + l] + sred2[((2 + wx) * NTI + nt) * 16 + l];
        int i = n0 + wx * 64 + nt * 16 + l;
        size_t idx = ((size_t)bz * gridDim.y + blockIdx.y) * N + i;
        pmax_g[idx] = cm[nt];
        psum_g[idx] = stot;
      }
    }
  }
}

// ---------------- softmax combine + apply (softmax over j = St's row dim) ----------------
__global__ __launch_bounds__(256) void softmax_comb(const float* __restrict__ pmax,
                                                    const float* __restrict__ psum,
                                                    float* __restrict__ cmax, float* __restrict__ cinv) {
  int idx = blockIdx.x * 256 + threadIdx.x;  // b*NDIM + i
  int b = idx >> 12, i = idx & (NDIM - 1);
  float M = -1e30f;
  for (int bc = 0; bc < 32; bc++) M = fmaxf(M, pmax[((size_t)b * 32 + bc) * NDIM + i]);
  float s = 0.f;
  for (int bc = 0; bc < 32; bc++) {
    size_t o = ((size_t)b * 32 + bc) * NDIM + i;
    s += psum[o] * __expf(pmax[o] - M);
  }
  cmax[idx] = M;
  cinv[idx] = 1.0f / s;
}

__device__ __forceinline__ short bf16_bits(float v) {
  __hip_bfloat16 h = __float2bfloat16(v);
  union { __hip_bfloat16 h; short s; } u;
  u.h = h;
  return u.s;
}

// one block per (j-row, b); 256 threads x 16 bf16 = 4096 i's, 16B vector loads
__global__ __launch_bounds__(256) void softmax_apply(__hip_bfloat16* __restrict__ St,
                                                     const float* __restrict__ cmax,
                                                     const float* __restrict__ cinv) {
  int b = blockIdx.y;
  size_t row = blockIdx.x;
  int i0 = threadIdx.x * 16;
  __hip_bfloat16* p = St + ((size_t)b * NDIM + row) * NDIM + i0;
  const float4* pm = (const float4*)(cmax + (size_t)b * NDIM + i0);
  const float4* pz = (const float4*)(cinv + (size_t)b * NDIM + i0);
  bf16x8 d0 = *(const bf16x8*)p;
  bf16x8 d1 = *(const bf16x8*)(p + 8);
  float4 M4[4], Z4[4];
#pragma unroll
  for (int t = 0; t < 4; t++) { M4[t] = pm[t]; Z4[t] = pz[t]; }
  const float* Mf = (const float*)M4;
  const float* Zf = (const float*)Z4;
  bf16x8 o0, o1;
#pragma unroll
  for (int e = 0; e < 8; e++) {
    union { short s; __hip_bfloat16 h; } u; u.s = d0[e];
    o0[e] = bf16_bits(__expf(__bfloat162float(u.h) - Mf[e]) * Zf[e]);
  }
#pragma unroll
  for (int e = 0; e < 8; e++) {
    union { short s; __hip_bfloat16 h; } u; u.s = d1[e];
    o1[e] = bf16_bits(__expf(__bfloat162float(u.h) - Mf[8 + e]) * Zf[8 + e]);
  }
  *(bf16x8*)p = o0;
  *(bf16x8*)(p + 8) = o1;
}

extern "C" void kernel_launch(void* const* d_in, const int* in_sizes, int n_in,
                              void* d_out, int out_size, void* d_ws, size_t ws_size,
                              hipStream_t stream) {
  const float* x      = (const float*)d_in[0];
  const float* norm_w = (const float*)d_in[1];
  const float* norm_b = (const float*)d_in[2];
  const float* wq = (const float*)d_in[3];
  const float* bq = (const float*)d_in[4];
  const float* wk = (const float*)d_in[5];
  const float* bk = (const float*)d_in[6];
  const float* wv = (const float*)d_in[7];
  const float* bv = (const float*)d_in[8];
  const float* wp = (const float*)d_in[9];
  const float* bp = (const float*)d_in[10];
  float* out = (float*)d_out;

  const long CN = (long)CDIM * NDIM;
  const long NN = (long)NDIM * NDIM;
  char* p = (char*)d_ws;
  auto carve = [&](size_t bytes) { char* r = p; p += (bytes + 255) & ~(size_t)255; return r; };
  __hip_bfloat16* h_t  = (__hip_bfloat16*)carve(BATCH * CN * 2);  // [B,N,C]
  __hip_bfloat16* wb   = (__hip_bfloat16*)carve(4 * 512 * 512 * 2);
  __hip_bfloat16* q_t  = (__hip_bfloat16*)carve(BATCH * CN * 2);  // [B,N,C]
  __hip_bfloat16* k_t  = (__hip_bfloat16*)carve(BATCH * CN * 2);  // [B,N,C]
  __hip_bfloat16* vb   = (__hip_bfloat16*)carve(BATCH * CN * 2);  // [B,C,N]
  __hip_bfloat16* ht2  = (__hip_bfloat16*)carve(BATCH * CN * 2);  // [B,N,C]
  __hip_bfloat16* St   = (__hip_bfloat16*)carve(BATCH * NN * 2);  // [B,N,N] S^T -> P^T
  float2* stats = (float2*)carve(BATCH * NGROUPS * sizeof(float2));
  float2* gnpart = (float2*)carve(1024 * sizeof(float2));
  float* pmax = (float*)carve((size_t)BATCH * 32 * NDIM * 4);
  float* psum = (float*)carve((size_t)BATCH * 32 * NDIM * 4);
  float* cmax = (float*)carve(BATCH * NDIM * 4);
  float* cinv = (float*)carve(BATCH * NDIM * 4);
  __hip_bfloat16* wbq = wb;
  __hip_bfloat16* wbk = wb + 262144;
  __hip_bfloat16* wbv = wb + 524288;
  __hip_bfloat16* wbp = wb + 786432;

  const float scale = 0.044194173824159216f;  // 512^-0.5

  gn_stats_p1<<<dim3(1024), 256, 0, stream>>>(x, gnpart);
  gn_stats_p2<<<dim3(1), 64, 0, stream>>>(gnpart, stats);
  gn_apply_t<<<dim3(NDIM / 64, CDIM / 64, BATCH), 256, 0, stream>>>(x, stats, norm_w, norm_b, h_t);
  cvt_w<<<dim3(1024), 256, 0, stream>>>(wq, wk, wv, wp, wb);

  // q_t = h_t @ wq^T + bq -> [N, C]   (SWIZ: A=h_t shared by 8 x-partners)
  mfma_gemm_nt<128, 64, 2, false, 1, false, true, 2><<<dim3(8, 32, BATCH), 256, 0, stream>>>(
      h_t, wbq, bq, nullptr, q_t, nullptr, nullptr, NDIM, CDIM, CDIM, CN, 0, CN, 1.0f);
  // k_t = h_t @ wk^T + bk -> [N, C]
  mfma_gemm_nt<128, 64, 2, false, 1, false, true, 2><<<dim3(8, 32, BATCH), 256, 0, stream>>>(
      h_t, wbk, bk, nullptr, k_t, nullptr, nullptr, NDIM, CDIM, CDIM, CN, 0, CN, 1.0f);
  // v = wv @ h_t^T + bv -> [C, N]   (grid (32,8): B-partners already same-XCD)
  mfma_gemm_nt<64, 128, 1, false, 1, false, false, 2><<<dim3(32, 8, BATCH), 256, 0, stream>>>(
      wbv, h_t, bv, nullptr, vb, nullptr, nullptr, CDIM, NDIM, CDIM, 0, CN, CN, 1.0f);
  // St = k_t @ q_t^T * scale -> [N, N], fused column stats; 3 blocks/CU
  mfma_gemm_nt<128, 128, 0, false, 1, true, false, 3><<<dim3(32, 32, BATCH), 256, 0, stream>>>(
      k_t, q_t, nullptr, nullptr, St, pmax, psum, NDIM, NDIM, CDIM, CN, CN, NN, scale);
  softmax_comb<<<dim3(32), 256, 0, stream>>>(pmax, psum, cmax, cinv);
  softmax_apply<<<dim3(NDIM, BATCH), 256, 0, stream>>>(St, cmax, cinv);
  // ht2 = Pt @ v^T -> [N, C]   (SWIZ: A=St is the 64MB operand)
  mfma_gemm_nt<128, 64, 0, false, 1, false, true, 2><<<dim3(8, 32, BATCH), 256, 0, stream>>>(
      St, vb, nullptr, nullptr, ht2, nullptr, nullptr, NDIM, CDIM, NDIM, NN, CN, CN, 1.0f);
  // out = wp @ ht2^T + bp + x -> [C, N] fp32
  mfma_gemm_nt<64, 128, 1, true, 0, false, false, 2><<<dim3(32, 8, BATCH), 256, 0, stream>>>(
      wbp, ht2, bp, x, out, nullptr, nullptr, CDIM, NDIM, CDIM, 0, CN, CN, 1.0f);
}

// Round 9
// 259.778 us; speedup vs baseline: 1.1884x; 1.0446x over previous
//
#include <hip/hip_runtime.h>
#include <hip/hip_bf16.h>

// B=2, C=512, H=W=64 -> N=4096, 32 groups of 16 channels
#define BATCH 2
#define CDIM 512
#define NDIM 4096
#define NGROUPS 32
#define CHPG 16
#define GN_EPS 1e-6f

typedef __attribute__((ext_vector_type(8))) short bf16x8;   // 8 bf16 = 4 VGPRs
typedef __attribute__((ext_vector_type(4))) float f32x4;

__device__ __forceinline__ void gl_lds16(const void* g, void* lds) {
  __builtin_amdgcn_global_load_lds((__attribute__((address_space(1))) void*)(g),
                                   (__attribute__((address_space(3))) void*)(lds), 16, 0, 0);
}

template <int N>
__device__ __forceinline__ void wait_vmcnt() {
  if constexpr (N == 1) asm volatile("s_waitcnt vmcnt(1)" ::: "memory");
  else if constexpr (N == 2) asm volatile("s_waitcnt vmcnt(2)" ::: "memory");
  else if constexpr (N == 3) asm volatile("s_waitcnt vmcnt(3)" ::: "memory");
  else if constexpr (N == 4) asm volatile("s_waitcnt vmcnt(4)" ::: "memory");
  else if constexpr (N == 5) asm volatile("s_waitcnt vmcnt(5)" ::: "memory");
  else if constexpr (N == 6) asm volatile("s_waitcnt vmcnt(6)" ::: "memory");
  else asm volatile("s_waitcnt vmcnt(8)" ::: "memory");
}

__device__ __forceinline__ void raw_barrier() {
  asm volatile("s_barrier" ::: "memory");
}

// ---------------- GroupNorm stats, two-stage ----------------
__global__ __launch_bounds__(256) void gn_stats_p1(const float* __restrict__ x,
                                                   float2* __restrict__ part) {
  int blk = blockIdx.x;
  int chunk = blk & 15, bg = blk >> 4;
  const float4* p = (const float4*)(x + (size_t)bg * (CHPG * NDIM) + chunk * 4096);
  float s = 0.f, ss = 0.f;
#pragma unroll
  for (int t = 0; t < 4; t++) {
    float4 v = p[threadIdx.x + t * 256];
    s += v.x + v.y + v.z + v.w;
    ss += v.x * v.x + v.y * v.y + v.z * v.z + v.w * v.w;
  }
  int w = threadIdx.x >> 6, l = threadIdx.x & 63;
#pragma unroll
  for (int off = 32; off > 0; off >>= 1) {
    s += __shfl_down(s, off);
    ss += __shfl_down(ss, off);
  }
  __shared__ float r1[4], r2[4];
  if (l == 0) { r1[w] = s; r2[w] = ss; }
  __syncthreads();
  if (threadIdx.x == 0)
    part[blk] = make_float2(r1[0] + r1[1] + r1[2] + r1[3], r2[0] + r2[1] + r2[2] + r2[3]);
}

__global__ __launch_bounds__(64) void gn_stats_p2(const float2* __restrict__ part,
                                                  float2* __restrict__ stats) {
  int bg = threadIdx.x;  // 64
  float s = 0.f, ss = 0.f;
#pragma unroll
  for (int c = 0; c < 16; c++) {
    float2 v = part[bg * 16 + c];
    s += v.x; ss += v.y;
  }
  const float inv = 1.0f / (CHPG * NDIM);
  float mean = s * inv;
  float var = ss * inv - mean * mean;
  stats[bg] = make_float2(mean, rsqrtf(var + GN_EPS));
}

// ------ GroupNorm apply + transpose to channel-last bf16: h_t[b][n][c] ------
__global__ __launch_bounds__(256) void gn_apply_t(const float* __restrict__ x,
                                                  const float2* __restrict__ stats,
                                                  const float* __restrict__ w,
                                                  const float* __restrict__ bias,
                                                  __hip_bfloat16* __restrict__ ht) {
  __shared__ __hip_bfloat16 tile[64][66];
  int b = blockIdx.z, c0 = blockIdx.y * 64, n0 = blockIdx.x * 64;
  int tq = threadIdx.x >> 6;
  int tl = threadIdx.x & 63;
#pragma unroll
  for (int i = 0; i < 16; i++) {
    int cl = tq * 16 + i;
    int c = c0 + cl;
    float2 st = stats[b * NGROUPS + (c >> 4)];
    float v = x[((size_t)b * CDIM + c) * NDIM + n0 + tl];
    v = (v - st.x) * st.y * w[c] + bias[c];
    tile[tl][cl] = __float2bfloat16(v);
  }
  __syncthreads();
#pragma unroll
  for (int i = 0; i < 16; i++) {
    int nl = tq * 16 + i;
    ht[((size_t)b * NDIM + n0 + nl) * CDIM + c0 + tl] = tile[nl][tl];
  }
}

// ------------- fp32 -> bf16 for the four 512x512 weights -------------
__global__ __launch_bounds__(256) void cvt_w(const float* __restrict__ a, const float* __restrict__ b,
                                             const float* __restrict__ c, const float* __restrict__ d,
                                             __hip_bfloat16* __restrict__ o) {
  int i = blockIdx.x * 256 + threadIdx.x;
  o[i]          = __float2bfloat16(a[i]);
  o[i + 262144] = __float2bfloat16(b[i]);
  o[i + 524288] = __float2bfloat16(c[i]);
  o[i + 786432] = __float2bfloat16(d[i]);
}

// ---------------- MFMA NT GEMM, pipelined + LDS-swizzled ----------------
// C[m][n] = scale * sum_k A[m][k]*B[n][k]  (+bias) (+res)
// A: [M,K] bf16, B: [N,K] bf16, row-major. BK = 32*KU, 4 waves (2x2).
// LDS layout: row-slab of SB=64*KU bytes; column-quads rotated per row so
// fragment b128 reads hit 8 distinct 16B bank-groups per 8-lane phase
// (conflict-free). Staging compensates by permuting each lane's global
// column source (global_load_lds lane->base+l*16 is fixed).
// OUT_MODE: 0 f32, 1 bf16. BIAS_MODE: 0 none, 1 bias[m], 2 bias[n].
// STATS (128x128 only): per-block column max/sum-of-exp. SWIZ (grid (8,32,z)):
// co-locate the 8 blocks sharing an A row-tile on one XCD.
template <int MT, int NT, int KU, int BIAS_MODE, bool HAS_RES, int OUT_MODE, bool STATS, bool SWIZ, int MINB>
__global__ __launch_bounds__(256, MINB) void mfma_gemm_nt(
    const __hip_bfloat16* __restrict__ A, const __hip_bfloat16* __restrict__ B,
    const float* __restrict__ bias, const float* __restrict__ res,
    void* __restrict__ Cout, float* __restrict__ pmax_g, float* __restrict__ psum_g,
    int M, int N, int K, long sA, long sB, long sC, float scale) {
  constexpr int MTI = MT / 32, NTI = NT / 32;   // 16x16 acc tiles per wave
  constexpr int SB = 64 * KU;                   // bytes per row k-slab
  constexpr int ABYT = MT * SB, BBYT = NT * SB;
  constexpr int BUFB = ABYT + BBYT;
  constexpr int AISS = MT * KU / 64, BISS = NT * KU / 64;
  constexpr int NL = AISS + BISS;               // gl_lds16 issues per wave per tile
  constexpr int RPI = 16 / KU;                  // rows per issue
  __shared__ char smem[2 * BUFB];
  const int tid = threadIdx.x;
  const int w = tid >> 6, l = tid & 63;
  const int wy = w >> 1, wx = w & 1;
  const int bz = blockIdx.z;
  int bx = blockIdx.x, by = blockIdx.y;
  if constexpr (SWIZ) {
    int l2 = by * 8 + bx;
    int xcd = l2 & 7, s = l2 >> 3;
    by = xcd + (s & 3) * 8;
    bx = s >> 2;
  }
  const int m0 = by * MT, n0 = bx * NT;
  f32x4 acc[MTI][NTI] = {};

  // staging source column swizzle (bytes within the SB row-slab)
  int so;
  if constexpr (KU == 1) so = (((l & 3) - (l >> 2) - (l >> 4)) & 3) * 16;
  else                   so = (((l & 7) - (l >> 3)) & 7) * 16;
  const int lrow = (KU == 1) ? (l >> 2) : (l >> 3);
  const int arow = w * (MT / 4) + lrow;
  const int brow = w * (NT / 4) + lrow;
  const char* Ag = (const char*)A + ((size_t)bz * sA + (size_t)(m0 + arow) * K) * 2 + so;
  const char* Bg = (const char*)B + ((size_t)bz * sB + (size_t)(n0 + brow) * K) * 2 + so;
  const size_t iadv = (size_t)RPI * K * 2;   // per-issue global row advance
  const int woffA = w * (MT / 4) * SB;
  const int woffB = ABYT + w * (NT / 4) * SB;

  auto issue = [&](int buf) {
    char* base = smem + buf * BUFB;
#pragma unroll
    for (int i = 0; i < AISS; i++) gl_lds16(Ag + i * iadv, base + woffA + i * 1024);
#pragma unroll
    for (int i = 0; i < BISS; i++) gl_lds16(Bg + i * iadv, base + woffB + i * 1024);
    Ag += SB; Bg += SB;
  };

  // fragment-read column offsets (per KU half)
  const int x = l & 15;
  int qr0, qr1 = 0;
  if constexpr (KU == 1) {
    qr0 = (((l >> 4) + x + (x >> 2)) & 3) * 16;
  } else {
    qr0 = (((l >> 4) + (l & 7)) & 7) * 16;
    qr1 = (((l >> 4) + 4 + (l & 7)) & 7) * 16;
  }

  issue(0);  // prologue: tile 0 -> buf 0
  const int T = K / (32 * KU);
  for (int t = 0; t < T; t++) {
    issue((t + 1) & 1);       // prefetch tile t+1 (last iter overshoots <=SB within ws)
    wait_vmcnt<NL>();         // tile t's loads done; t+1's stay in flight
    raw_barrier();
    const char* Asb = smem + (t & 1) * BUFB;
    const char* Bsb = Asb + ABYT;
#pragma unroll
    for (int h = 0; h < KU; h++) {
      const int q = (h == 0) ? qr0 : qr1;
      bf16x8 af[MTI], bfr[NTI];
#pragma unroll
      for (int mt = 0; mt < MTI; mt++)
        af[mt] = *(const bf16x8*)(Asb + (wy * (MT / 2) + mt * 16 + x) * SB + q);
#pragma unroll
      for (int nt = 0; nt < NTI; nt++)
        bfr[nt] = *(const bf16x8*)(Bsb + (wx * (NT / 2) + nt * 16 + x) * SB + q);
#pragma unroll
      for (int mt = 0; mt < MTI; mt++)
#pragma unroll
        for (int nt = 0; nt < NTI; nt++)
          acc[mt][nt] = __builtin_amdgcn_mfma_f32_16x16x32_bf16(af[mt], bfr[nt], acc[mt][nt], 0, 0, 0);
    }
    raw_barrier();            // all waves done reading buf[t&1] before tile t+2 overwrites it
  }
  // epilogue: D row = (l>>4)*4 + r, col = l&15
  const size_t cbase = (size_t)bz * sC;
#pragma unroll
  for (int mt = 0; mt < MTI; mt++) {
#pragma unroll
    for (int r = 0; r < 4; r++) {
      const int m = m0 + wy * (MT / 2) + mt * 16 + (l >> 4) * 4 + r;
      float bv = (BIAS_MODE == 1) ? bias[m] : 0.f;
#pragma unroll
      for (int nt = 0; nt < NTI; nt++) {
        const int n = n0 + wx * (NT / 2) + nt * 16 + (l & 15);
        float v = acc[mt][nt][r] * scale + bv;
        if (BIAS_MODE == 2) v += bias[n];
        if (HAS_RES) v += res[cbase + (size_t)m * N + n];
        if (OUT_MODE == 0) ((float*)Cout)[cbase + (size_t)m * N + n] = v;
        else ((__hip_bfloat16*)Cout)[cbase + (size_t)m * N + n] = __float2bfloat16(v);
      }
    }
  }
  if constexpr (STATS) {
    float* sred1 = (float*)smem;          // [w][nt][16]
    float* sred2 = (float*)smem + 512;
    float cm[NTI];
    __syncthreads();  // ensure K-loop LDS reads done before reuse
#pragma unroll
    for (int nt = 0; nt < NTI; nt++) {
      float m = -1e30f;
#pragma unroll
      for (int mt = 0; mt < MTI; mt++)
#pragma unroll
        for (int r = 0; r < 4; r++) m = fmaxf(m, acc[mt][nt][r] * scale);
      m = fmaxf(m, __shfl_xor(m, 16));
      m = fmaxf(m, __shfl_xor(m, 32));
      if (l < 16) sred1[(w * NTI + nt) * 16 + l] = m;
    }
    __syncthreads();
#pragma unroll
    for (int nt = 0; nt < NTI; nt++) {
      float bm = fmaxf(sred1[(wx * NTI + nt) * 16 + (l & 15)],
                       sred1[((2 + wx) * NTI + nt) * 16 + (l & 15)]);
      cm[nt] = bm;
      float s = 0.f;
#pragma unroll
      for (int mt = 0; mt < MTI; mt++)
#pragma unroll
        for (int r = 0; r < 4; r++) s += __expf(acc[mt][nt][r] * scale - bm);
      s += __shfl_xor(s, 16);
      s += __shfl_xor(s, 32);
      if (l < 16) sred2[(w * NTI + nt) * 16 + l] = s;
    }
    __syncthreads();
    if (wy == 0 && l < 16) {
#pragma unroll
      for (int nt = 0; nt < NTI; nt++) {
        float stot = sred2[(wx * NTI + nt) * 16 + l] + sred2[((2 + wx) * NTI + nt) * 16 + l];
        int i = n0 + wx * 64 + nt * 16 + l;
        size_t idx = ((size_t)bz * gridDim.y + blockIdx.y) * N + i;
        pmax_g[idx] = cm[nt];
        psum_g[idx] = stot;
      }
    }
  }
}

// ---------------- softmax combine + apply (softmax over j = St's row dim) ----------------
__global__ __launch_bounds__(256) void softmax_comb(const float* __restrict__ pmax,
                                                    const float* __restrict__ psum,
                                                    float* __restrict__ cmax, float* __restrict__ cinv) {
  int idx = blockIdx.x * 256 + threadIdx.x;  // b*NDIM + i
  int b = idx >> 12, i = idx & (NDIM - 1);
  float M = -1e30f;
  for (int bc = 0; bc < 32; bc++) M = fmaxf(M, pmax[((size_t)b * 32 + bc) * NDIM + i]);
  float s = 0.f;
  for (int bc = 0; bc < 32; bc++) {
    size_t o = ((size_t)b * 32 + bc) * NDIM + i;
    s += psum[o] * __expf(pmax[o] - M);
  }
  cmax[idx] = M;
  cinv[idx] = 1.0f / s;
}

__device__ __forceinline__ short bf16_bits(float v) {
  __hip_bfloat16 h = __float2bfloat16(v);
  union { __hip_bfloat16 h; short s; } u;
  u.h = h;
  return u.s;
}

// one block per (j-row, b); 256 threads x 16 bf16 = 4096 i's, 16B vector loads
__global__ __launch_bounds__(256) void softmax_apply(__hip_bfloat16* __restrict__ St,
                                                     const float* __restrict__ cmax,
                                                     const float* __restrict__ cinv) {
  int b = blockIdx.y;
  size_t row = blockIdx.x;
  int i0 = threadIdx.x * 16;
  __hip_bfloat16* p = St + ((size_t)b * NDIM + row) * NDIM + i0;
  const float4* pm = (const float4*)(cmax + (size_t)b * NDIM + i0);
  const float4* pz = (const float4*)(cinv + (size_t)b * NDIM + i0);
  bf16x8 d0 = *(const bf16x8*)p;
  bf16x8 d1 = *(const bf16x8*)(p + 8);
  float4 M4[4], Z4[4];
#pragma unroll
  for (int t = 0; t < 4; t++) { M4[t] = pm[t]; Z4[t] = pz[t]; }
  const float* Mf = (const float*)M4;
  const float* Zf = (const float*)Z4;
  bf16x8 o0, o1;
#pragma unroll
  for (int e = 0; e < 8; e++) {
    union { short s; __hip_bfloat16 h; } u; u.s = d0[e];
    o0[e] = bf16_bits(__expf(__bfloat162float(u.h) - Mf[e]) * Zf[e]);
  }
#pragma unroll
  for (int e = 0; e < 8; e++) {
    union { short s; __hip_bfloat16 h; } u; u.s = d1[e];
    o1[e] = bf16_bits(__expf(__bfloat162float(u.h) - Mf[8 + e]) * Zf[8 + e]);
  }
  *(bf16x8*)p = o0;
  *(bf16x8*)(p + 8) = o1;
}

extern "C" void kernel_launch(void* const* d_in, const int* in_sizes, int n_in,
                              void* d_out, int out_size, void* d_ws, size_t ws_size,
                              hipStream_t stream) {
  const float* x      = (const float*)d_in[0];
  const float* norm_w = (const float*)d_in[1];
  const float* norm_b = (const float*)d_in[2];
  const float* wq = (const float*)d_in[3];
  const float* bq = (const float*)d_in[4];
  const float* wk = (const float*)d_in[5];
  const float* bk = (const float*)d_in[6];
  const float* wv = (const float*)d_in[7];
  const float* bv = (const float*)d_in[8];
  const float* wp = (const float*)d_in[9];
  const float* bp = (const float*)d_in[10];
  float* out = (float*)d_out;

  const long CN = (long)CDIM * NDIM;
  const long NN = (long)NDIM * NDIM;
  char* p = (char*)d_ws;
  auto carve = [&](size_t bytes) { char* r = p; p += (bytes + 255) & ~(size_t)255; return r; };
  __hip_bfloat16* h_t  = (__hip_bfloat16*)carve(BATCH * CN * 2);  // [B,N,C]
  __hip_bfloat16* wb   = (__hip_bfloat16*)carve(4 * 512 * 512 * 2);
  __hip_bfloat16* q_t  = (__hip_bfloat16*)carve(BATCH * CN * 2);  // [B,N,C]
  __hip_bfloat16* k_t  = (__hip_bfloat16*)carve(BATCH * CN * 2);  // [B,N,C]
  __hip_bfloat16* vb   = (__hip_bfloat16*)carve(BATCH * CN * 2);  // [B,C,N]
  __hip_bfloat16* ht2  = (__hip_bfloat16*)carve(BATCH * CN * 2);  // [B,N,C]
  __hip_bfloat16* St   = (__hip_bfloat16*)carve(BATCH * NN * 2);  // [B,N,N] S^T -> P^T
  float2* stats = (float2*)carve(BATCH * NGROUPS * sizeof(float2));
  float2* gnpart = (float2*)carve(1024 * sizeof(float2));
  float* pmax = (float*)carve((size_t)BATCH * 32 * NDIM * 4);
  float* psum = (float*)carve((size_t)BATCH * 32 * NDIM * 4);
  float* cmax = (float*)carve(BATCH * NDIM * 4);
  float* cinv = (float*)carve(BATCH * NDIM * 4);
  __hip_bfloat16* wbq = wb;
  __hip_bfloat16* wbk = wb + 262144;
  __hip_bfloat16* wbv = wb + 524288;
  __hip_bfloat16* wbp = wb + 786432;

  const float scale = 0.044194173824159216f;  // 512^-0.5

  gn_stats_p1<<<dim3(1024), 256, 0, stream>>>(x, gnpart);
  gn_stats_p2<<<dim3(1), 64, 0, stream>>>(gnpart, stats);
  gn_apply_t<<<dim3(NDIM / 64, CDIM / 64, BATCH), 256, 0, stream>>>(x, stats, norm_w, norm_b, h_t);
  cvt_w<<<dim3(1024), 256, 0, stream>>>(wq, wk, wv, wp, wb);

  // q_t = h_t @ wq^T + bq -> [N, C]   (SWIZ: A=h_t shared by 8 x-partners; BK=64)
  mfma_gemm_nt<128, 64, 2, 2, false, 1, false, true, 2><<<dim3(8, 32, BATCH), 256, 0, stream>>>(
      h_t, wbq, bq, nullptr, q_t, nullptr, nullptr, NDIM, CDIM, CDIM, CN, 0, CN, 1.0f);
  // k_t = h_t @ wk^T + bk -> [N, C]
  mfma_gemm_nt<128, 64, 2, 2, false, 1, false, true, 2><<<dim3(8, 32, BATCH), 256, 0, stream>>>(
      h_t, wbk, bk, nullptr, k_t, nullptr, nullptr, NDIM, CDIM, CDIM, CN, 0, CN, 1.0f);
  // v = wv @ h_t^T + bv -> [C, N]   (grid (32,8): B-partners already same-XCD; BK=64)
  mfma_gemm_nt<64, 128, 2, 1, false, 1, false, false, 2><<<dim3(32, 8, BATCH), 256, 0, stream>>>(
      wbv, h_t, bv, nullptr, vb, nullptr, nullptr, CDIM, NDIM, CDIM, 0, CN, CN, 1.0f);
  // St = k_t @ q_t^T * scale -> [N, N], fused column stats; BK=32, 3 blocks/CU
  mfma_gemm_nt<128, 128, 1, 0, false, 1, true, false, 3><<<dim3(32, 32, BATCH), 256, 0, stream>>>(
      k_t, q_t, nullptr, nullptr, St, pmax, psum, NDIM, NDIM, CDIM, CN, CN, NN, scale);
  softmax_comb<<<dim3(32), 256, 0, stream>>>(pmax, psum, cmax, cinv);
  softmax_apply<<<dim3(NDIM, BATCH), 256, 0, stream>>>(St, cmax, cinv);
  // ht2 = Pt @ v^T -> [N, C]   (SWIZ: A=St is the 64MB operand; BK=64)
  mfma_gemm_nt<128, 64, 2, 0, false, 1, false, true, 2><<<dim3(8, 32, BATCH), 256, 0, stream>>>(
      St, vb, nullptr, nullptr, ht2, nullptr, nullptr, NDIM, CDIM, NDIM, NN, CN, CN, 1.0f);
  // out = wp @ ht2^T + bp + x -> [C, N] fp32
  mfma_gemm_nt<64, 128, 2, 1, true, 0, false, false, 2><<<dim3(32, 8, BATCH), 256, 0, stream>>>(
      wbp, ht2, bp, x, out, nullptr, nullptr, CDIM, NDIM, CDIM, 0, CN, CN, 1.0f);
}

// Round 10
// 232.964 us; speedup vs baseline: 1.3252x; 1.1151x over previous
//
#include <hip/hip_runtime.h>
#include <hip/hip_bf16.h>

// B=2, C=512, H=W=64 -> N=4096, 32 groups of 16 channels
#define BATCH 2
#define CDIM 512
#define NDIM 4096
#define NGROUPS 32
#define CHPG 16
#define GN_EPS 1e-6f

typedef __attribute__((ext_vector_type(8))) short bf16x8;   // 8 bf16 = 4 VGPRs
typedef __attribute__((ext_vector_type(4))) float f32x4;

__device__ __forceinline__ void gl_lds16(const void* g, void* lds) {
  __builtin_amdgcn_global_load_lds((__attribute__((address_space(1))) void*)(g),
                                   (__attribute__((address_space(3))) void*)(lds), 16, 0, 0);
}

template <int N>
__device__ __forceinline__ void wait_vmcnt() {
  if constexpr (N == 1) asm volatile("s_waitcnt vmcnt(1)" ::: "memory");
  else if constexpr (N == 2) asm volatile("s_waitcnt vmcnt(2)" ::: "memory");
  else if constexpr (N == 3) asm volatile("s_waitcnt vmcnt(3)" ::: "memory");
  else if constexpr (N == 4) asm volatile("s_waitcnt vmcnt(4)" ::: "memory");
  else if constexpr (N == 5) asm volatile("s_waitcnt vmcnt(5)" ::: "memory");
  else if constexpr (N == 6) asm volatile("s_waitcnt vmcnt(6)" ::: "memory");
  else asm volatile("s_waitcnt vmcnt(8)" ::: "memory");
}

__device__ __forceinline__ void raw_barrier() {
  asm volatile("s_barrier" ::: "memory");
}

__device__ __forceinline__ void drain_vm() {
  asm volatile("s_waitcnt vmcnt(0)" ::: "memory");
}

__device__ __forceinline__ short bf16_bits(float v) {
  __hip_bfloat16 h = __float2bfloat16(v);
  union { __hip_bfloat16 h; short s; } u;
  u.h = h;
  return u.s;
}

// ---------------- GroupNorm stats, two-stage ----------------
__global__ __launch_bounds__(256) void gn_stats_p1(const float* __restrict__ x,
                                                   float2* __restrict__ part) {
  int blk = blockIdx.x;
  int chunk = blk & 15, bg = blk >> 4;
  const float4* p = (const float4*)(x + (size_t)bg * (CHPG * NDIM) + chunk * 4096);
  float s = 0.f, ss = 0.f;
#pragma unroll
  for (int t = 0; t < 4; t++) {
    float4 v = p[threadIdx.x + t * 256];
    s += v.x + v.y + v.z + v.w;
    ss += v.x * v.x + v.y * v.y + v.z * v.z + v.w * v.w;
  }
  int w = threadIdx.x >> 6, l = threadIdx.x & 63;
#pragma unroll
  for (int off = 32; off > 0; off >>= 1) {
    s += __shfl_down(s, off);
    ss += __shfl_down(ss, off);
  }
  __shared__ float r1[4], r2[4];
  if (l == 0) { r1[w] = s; r2[w] = ss; }
  __syncthreads();
  if (threadIdx.x == 0)
    part[blk] = make_float2(r1[0] + r1[1] + r1[2] + r1[3], r2[0] + r2[1] + r2[2] + r2[3]);
}

__global__ __launch_bounds__(64) void gn_stats_p2(const float2* __restrict__ part,
                                                  float2* __restrict__ stats) {
  int bg = threadIdx.x;  // 64
  float s = 0.f, ss = 0.f;
#pragma unroll
  for (int c = 0; c < 16; c++) {
    float2 v = part[bg * 16 + c];
    s += v.x; ss += v.y;
  }
  const float inv = 1.0f / (CHPG * NDIM);
  float mean = s * inv;
  float var = ss * inv - mean * mean;
  stats[bg] = make_float2(mean, rsqrtf(var + GN_EPS));
}

// ------ GroupNorm apply + transpose to channel-last bf16: h_t[b][n][c] ------
__global__ __launch_bounds__(256) void gn_apply_t(const float* __restrict__ x,
                                                  const float2* __restrict__ stats,
                                                  const float* __restrict__ w,
                                                  const float* __restrict__ bias,
                                                  __hip_bfloat16* __restrict__ ht) {
  __shared__ __hip_bfloat16 tile[64][66];
  int b = blockIdx.z, c0 = blockIdx.y * 64, n0 = blockIdx.x * 64;
  int tq = threadIdx.x >> 6;
  int tl = threadIdx.x & 63;
#pragma unroll
  for (int i = 0; i < 16; i++) {
    int cl = tq * 16 + i;
    int c = c0 + cl;
    float2 st = stats[b * NGROUPS + (c >> 4)];
    float v = x[((size_t)b * CDIM + c) * NDIM + n0 + tl];
    v = (v - st.x) * st.y * w[c] + bias[c];
    tile[tl][cl] = __float2bfloat16(v);
  }
  __syncthreads();
#pragma unroll
  for (int i = 0; i < 16; i++) {
    int nl = tq * 16 + i;
    ht[((size_t)b * NDIM + n0 + nl) * CDIM + c0 + tl] = tile[nl][tl];
  }
}

// ------------- fp32 -> bf16 for the four 512x512 weights -------------
__global__ __launch_bounds__(256) void cvt_w(const float* __restrict__ a, const float* __restrict__ b,
                                             const float* __restrict__ c, const float* __restrict__ d,
                                             __hip_bfloat16* __restrict__ o) {
  int i = blockIdx.x * 256 + threadIdx.x;
  o[i]          = __float2bfloat16(a[i]);
  o[i + 262144] = __float2bfloat16(b[i]);
  o[i + 524288] = __float2bfloat16(c[i]);
  o[i + 786432] = __float2bfloat16(d[i]);
}

// ---------------- MFMA NT GEMM, pipelined + LDS-swizzled + repack epilogue ---
// C[m][n] = scale * sum_k A[m][k]*B[n][k]  (+bias) (+res)
// A: [M,K] bf16, B: [N,K] bf16, row-major. BK = 32*KU, 4 waves (2x2).
// K-loop: dbuf LDS, prefetch t+1, vmcnt(NL), raw barriers. Staging column
// swizzle keeps fragment ds_read_b128 conflict-free.
// Epilogue: values -> LDS (padded rows) -> coalesced dwordx4 global stores.
// EXPZ: value = exp(value); emit per-(i-half-tile) row sums to zsum_g
//       [b][bx*2+wx][m] (for deferred softmax normalization).
// SCALEM: value *= cinv_g[b][m]  (applies 1/Z[j] in PV).
// OUT_MODE: 0 f32, 1 bf16. BIAS_MODE: 0 none, 1 bias[m], 2 bias[n].
// HAS_RES: residual added during store phase (fp32 out only).
// SWIZ (grid (8,32,z)): co-locate 8 A-sharing blocks on one XCD.
template <int MT, int NT, int KU, int BIAS_MODE, bool HAS_RES, int OUT_MODE,
          bool EXPZ, bool SCALEM, bool SWIZ, int MINB>
__global__ __launch_bounds__(256, MINB) void mfma_gemm_nt(
    const __hip_bfloat16* __restrict__ A, const __hip_bfloat16* __restrict__ B,
    const float* __restrict__ bias, const float* __restrict__ res,
    void* __restrict__ Cout, float* __restrict__ zsum_g, const float* __restrict__ cinv_g,
    int M, int N, int K, long sA, long sB, long sC, float scale) {
  constexpr int MTI = MT / 32, NTI = NT / 32;   // 16x16 acc tiles per wave
  constexpr int SB = 64 * KU;                   // bytes per row k-slab
  constexpr int ABYT = MT * SB, BBYT = NT * SB;
  constexpr int BUFB = ABYT + BBYT;
  constexpr int AISS = MT * KU / 64, BISS = NT * KU / 64;
  constexpr int NL = AISS + BISS;
  constexpr int RPI = 16 / KU;                  // rows per staging issue
  constexpr int ES = (OUT_MODE == 0) ? 4 : 2;   // out element size
  constexpr int RS = NT * ES + 16;              // repack row stride (pad = 16B)
  constexpr int REPB = MT * RS;
  constexpr int SMEMB = (2 * BUFB > REPB) ? 2 * BUFB : REPB;
  constexpr int CPR = NT * ES / 16;             // 16B chunks per row
  constexpr int NCH = MT * CPR / 256;           // chunks per thread
  __shared__ char smem[SMEMB];
  const int tid = threadIdx.x;
  const int w = tid >> 6, l = tid & 63;
  const int wy = w >> 1, wx = w & 1;
  const int bz = blockIdx.z;
  int bx = blockIdx.x, by = blockIdx.y;
  if constexpr (SWIZ) {
    int l2 = by * 8 + bx;
    int xcd = l2 & 7, s = l2 >> 3;
    by = xcd + (s & 3) * 8;
    bx = s >> 2;
  }
  const int m0 = by * MT, n0 = bx * NT;
  f32x4 acc[MTI][NTI] = {};

  // staging source column swizzle (bytes within the SB row-slab)
  int so;
  if constexpr (KU == 1) so = (((l & 3) - (l >> 2) - (l >> 4)) & 3) * 16;
  else                   so = (((l & 7) - (l >> 3)) & 7) * 16;
  const int lrow = (KU == 1) ? (l >> 2) : (l >> 3);
  const int arow = w * (MT / 4) + lrow;
  const int brow = w * (NT / 4) + lrow;
  const char* Ag = (const char*)A + ((size_t)bz * sA + (size_t)(m0 + arow) * K) * 2 + so;
  const char* Bg = (const char*)B + ((size_t)bz * sB + (size_t)(n0 + brow) * K) * 2 + so;
  const size_t iadv = (size_t)RPI * K * 2;
  const int woffA = w * (MT / 4) * SB;
  const int woffB = ABYT + w * (NT / 4) * SB;

  auto issue = [&](int buf) {
    char* base = smem + buf * BUFB;
#pragma unroll
    for (int i = 0; i < AISS; i++) gl_lds16(Ag + i * iadv, base + woffA + i * 1024);
#pragma unroll
    for (int i = 0; i < BISS; i++) gl_lds16(Bg + i * iadv, base + woffB + i * 1024);
    Ag += SB; Bg += SB;
  };

  // fragment-read column offsets (per KU half)
  const int x = l & 15;
  int qr0, qr1 = 0;
  if constexpr (KU == 1) {
    qr0 = (((l >> 4) + x + (x >> 2)) & 3) * 16;
  } else {
    qr0 = (((l >> 4) + (l & 7)) & 7) * 16;
    qr1 = (((l >> 4) + 4 + (l & 7)) & 7) * 16;
  }

  issue(0);
  const int T = K / (32 * KU);
  for (int t = 0; t < T; t++) {
    issue((t + 1) & 1);       // prefetch t+1 (last iter overshoots <=SB, lands in ws)
    wait_vmcnt<NL>();
    raw_barrier();
    const char* Asb = smem + (t & 1) * BUFB;
    const char* Bsb = Asb + ABYT;
#pragma unroll
    for (int h = 0; h < KU; h++) {
      const int q = (h == 0) ? qr0 : qr1;
      bf16x8 af[MTI], bfr[NTI];
#pragma unroll
      for (int mt = 0; mt < MTI; mt++)
        af[mt] = *(const bf16x8*)(Asb + (wy * (MT / 2) + mt * 16 + x) * SB + q);
#pragma unroll
      for (int nt = 0; nt < NTI; nt++)
        bfr[nt] = *(const bf16x8*)(Bsb + (wx * (NT / 2) + nt * 16 + x) * SB + q);
#pragma unroll
      for (int mt = 0; mt < MTI; mt++)
#pragma unroll
        for (int nt = 0; nt < NTI; nt++)
          acc[mt][nt] = __builtin_amdgcn_mfma_f32_16x16x32_bf16(af[mt], bfr[nt], acc[mt][nt], 0, 0, 0);
    }
    raw_barrier();            // all waves done reading buf before t+2 overwrites
  }

  // ---- epilogue: value phase -> LDS repack -> coalesced store phase ----
  drain_vm();      // stray tile-T prefetch landed
  raw_barrier();   // everyone drained before smem reuse
  const size_t cbase = (size_t)bz * sC;
#pragma unroll
  for (int mt = 0; mt < MTI; mt++) {
#pragma unroll
    for (int r = 0; r < 4; r++) {
      const int row = wy * (MT / 2) + mt * 16 + (l >> 4) * 4 + r;  // block-local m
      float bvm = (BIAS_MODE == 1) ? bias[m0 + row] : 0.f;
      float cm = 1.f;
      if constexpr (SCALEM) cm = cinv_g[(size_t)bz * M + m0 + row];
      float z = 0.f;
#pragma unroll
      for (int nt = 0; nt < NTI; nt++) {
        const int nl = wx * (NT / 2) + nt * 16 + x;
        float v = acc[mt][nt][r] * scale + bvm;
        if (BIAS_MODE == 2) v += bias[n0 + nl];
        if constexpr (EXPZ) { v = __expf(v); z += v; }
        if constexpr (SCALEM) v *= cm;
        if (OUT_MODE == 0) *(float*)(smem + row * RS + nl * 4) = v;
        else *(short*)(smem + row * RS + nl * 2) = bf16_bits(v);
      }
      if constexpr (EXPZ) {
        z += __shfl_xor(z, 1); z += __shfl_xor(z, 2);
        z += __shfl_xor(z, 4); z += __shfl_xor(z, 8);
        if (x == 0)
          zsum_g[((size_t)bz * 64 + bx * 2 + wx) * M + m0 + row] = z;
      }
    }
  }
  __syncthreads();
#pragma unroll
  for (int i = 0; i < NCH; i++) {
    const int g = i * 256 + tid;
    const int row = g / CPR;
    const int off = (g % CPR) * 16;
    char* dst = (char*)Cout + (cbase + (size_t)(m0 + row) * N + n0) * ES + off;
    if (OUT_MODE == 0) {
      float4 d = *(float4*)(smem + row * RS + off);
      if constexpr (HAS_RES) {
        float4 rv = *(const float4*)((const char*)res + (cbase + (size_t)(m0 + row) * N + n0) * 4 + off);
        d.x += rv.x; d.y += rv.y; d.z += rv.z; d.w += rv.w;
      }
      *(float4*)dst = d;
    } else {
      int4 d = *(int4*)(smem + row * RS + off);
      *(int4*)dst = d;
    }
  }
}

// ---------------- Z combine: cinv[b][j] = 1 / sum_p zsum[b][p][j] ----------------
__global__ __launch_bounds__(256) void zcomb(const float* __restrict__ zsum,
                                             float* __restrict__ cinv) {
  int idx = blockIdx.x * 256 + threadIdx.x;  // b*NDIM + j, 8192 total
  int b = idx >> 12, j = idx & (NDIM - 1);
  float s = 0.f;
#pragma unroll 8
  for (int p = 0; p < 64; p++) s += zsum[((size_t)b * 64 + p) * NDIM + j];
  cinv[idx] = 1.0f / s;
}

extern "C" void kernel_launch(void* const* d_in, const int* in_sizes, int n_in,
                              void* d_out, int out_size, void* d_ws, size_t ws_size,
                              hipStream_t stream) {
  const float* x      = (const float*)d_in[0];
  const float* norm_w = (const float*)d_in[1];
  const float* norm_b = (const float*)d_in[2];
  const float* wq = (const float*)d_in[3];
  const float* bq = (const float*)d_in[4];
  const float* wk = (const float*)d_in[5];
  const float* bk = (const float*)d_in[6];
  const float* wv = (const float*)d_in[7];
  const float* bv = (const float*)d_in[8];
  const float* wp = (const float*)d_in[9];
  const float* bp = (const float*)d_in[10];
  float* out = (float*)d_out;

  const long CN = (long)CDIM * NDIM;
  const long NN = (long)NDIM * NDIM;
  char* p = (char*)d_ws;
  auto carve = [&](size_t bytes) { char* r = p; p += (bytes + 255) & ~(size_t)255; return r; };
  __hip_bfloat16* h_t  = (__hip_bfloat16*)carve(BATCH * CN * 2);  // [B,N,C]
  __hip_bfloat16* wb   = (__hip_bfloat16*)carve(4 * 512 * 512 * 2);
  __hip_bfloat16* q_t  = (__hip_bfloat16*)carve(BATCH * CN * 2);  // [B,N,C]
  __hip_bfloat16* k_t  = (__hip_bfloat16*)carve(BATCH * CN * 2);  // [B,N,C]
  __hip_bfloat16* vb   = (__hip_bfloat16*)carve(BATCH * CN * 2);  // [B,C,N]
  __hip_bfloat16* ht2  = (__hip_bfloat16*)carve(BATCH * CN * 2);  // [B,N,C]
  __hip_bfloat16* St   = (__hip_bfloat16*)carve(BATCH * NN * 2);  // [B,N,N] E^T = exp(S^T)
  float* zsum  = (float*)carve((size_t)BATCH * 64 * NDIM * 4);    // after St (stray-prefetch slack)
  float* cinv  = (float*)carve(BATCH * NDIM * 4);
  float2* stats = (float2*)carve(BATCH * NGROUPS * sizeof(float2));
  float2* gnpart = (float2*)carve(1024 * sizeof(float2));
  __hip_bfloat16* wbq = wb;
  __hip_bfloat16* wbk = wb + 262144;
  __hip_bfloat16* wbv = wb + 524288;
  __hip_bfloat16* wbp = wb + 786432;

  const float scale = 0.044194173824159216f;  // 512^-0.5

  gn_stats_p1<<<dim3(1024), 256, 0, stream>>>(x, gnpart);
  gn_stats_p2<<<dim3(1), 64, 0, stream>>>(gnpart, stats);
  gn_apply_t<<<dim3(NDIM / 64, CDIM / 64, BATCH), 256, 0, stream>>>(x, stats, norm_w, norm_b, h_t);
  cvt_w<<<dim3(1024), 256, 0, stream>>>(wq, wk, wv, wp, wb);

  // q_t = h_t @ wq^T + bq -> [N, C]   (SWIZ; BK=64)
  mfma_gemm_nt<128, 64, 2, 2, false, 1, false, false, true, 2><<<dim3(8, 32, BATCH), 256, 0, stream>>>(
      h_t, wbq, bq, nullptr, q_t, nullptr, nullptr, NDIM, CDIM, CDIM, CN, 0, CN, 1.0f);
  // k_t = h_t @ wk^T + bk -> [N, C]
  mfma_gemm_nt<128, 64, 2, 2, false, 1, false, false, true, 2><<<dim3(8, 32, BATCH), 256, 0, stream>>>(
      h_t, wbk, bk, nullptr, k_t, nullptr, nullptr, NDIM, CDIM, CDIM, CN, 0, CN, 1.0f);
  // v = wv @ h_t^T + bv -> [C, N]   (BK=64)
  mfma_gemm_nt<64, 128, 2, 1, false, 1, false, false, false, 2><<<dim3(32, 8, BATCH), 256, 0, stream>>>(
      wbv, h_t, bv, nullptr, vb, nullptr, nullptr, CDIM, NDIM, CDIM, 0, CN, CN, 1.0f);
  // E^T = exp(k_t @ q_t^T * scale) -> [N, N] bf16, fused partial Z row-sums
  mfma_gemm_nt<128, 128, 1, 0, false, 1, true, false, false, 3><<<dim3(32, 32, BATCH), 256, 0, stream>>>(
      k_t, q_t, nullptr, nullptr, St, zsum, nullptr, NDIM, NDIM, CDIM, CN, CN, NN, scale);
  zcomb<<<dim3(32), 256, 0, stream>>>(zsum, cinv);
  // ht2 = diag-scale(cinv) applied to (E^T @ v^T) -> [N, C]   (SWIZ; BK=64)
  mfma_gemm_nt<128, 64, 2, 0, false, 1, false, true, true, 2><<<dim3(8, 32, BATCH), 256, 0, stream>>>(
      St, vb, nullptr, nullptr, ht2, nullptr, cinv, NDIM, CDIM, NDIM, NN, CN, CN, 1.0f);
  // out = wp @ ht2^T + bp + x -> [C, N] fp32 (residual fused in store phase)
  mfma_gemm_nt<64, 128, 2, 1, true, 0, false, false, false, 2><<<dim3(32, 8, BATCH), 256, 0, stream>>>(
      wbp, ht2, bp, x, out, nullptr, nullptr, CDIM, NDIM, CDIM, 0, CN, CN, 1.0f);
}